// Round 7
// baseline (396.501 us; speedup 1.0000x reference)
//
#include <hip/hip_runtime.h>
#include <math.h>

#define NN 50000
#define NE 800000

typedef float  f32x4  __attribute__((ext_vector_type(4)));
typedef __bf16 bf16x8 __attribute__((ext_vector_type(8)));

// ws layout: [0,256) m_agg_w (64 f32). [256,...) bf16 weight fragments,
// 16B chunks, fragment-linear (chunk = tile*64 + lane):
#define WE1F_OFF 0        // 5120: We1||Wg1  (kc<5, ct<16)  K 136->160
#define WE2F_OFF 5120     // 1024: We2       (kc<4, ct<4)
#define WN1F_OFF 6144     // 2048: Wn1       (kc<4, ct<8)
#define WN2F_OFF 8192     // 1024: Wn2       (kc<4, ct<4)
#define WW1F_OFF 9216     // 1536: Ww1       (kc<3, ct<8)   K 67->96
#define WW2F_OFF 10752    // 1024: Ww2       (kc<4, ct<4)
#define NCHUNKS  11776

__device__ inline bf16x8 pack8(float4 a, float4 b) {
    bf16x8 r;
    r[0] = (__bf16)a.x; r[1] = (__bf16)a.y; r[2] = (__bf16)a.z; r[3] = (__bf16)a.w;
    r[4] = (__bf16)b.x; r[5] = (__bf16)b.y; r[6] = (__bf16)b.z; r[7] = (__bf16)b.w;
    return r;
}

__device__ inline float4 add4(float4 a, float4 b) {
    a.x += b.x; a.y += b.y; a.z += b.z; a.w += b.w; return a;
}

// ---------------- weight fragment pre-pack ----------------
__global__ __launch_bounds__(256) void pack_weights(
    const float* __restrict__ We1, const float* __restrict__ Wg1,
    const float* __restrict__ We2, const float* __restrict__ Wn1,
    const float* __restrict__ Wn2, const float* __restrict__ Ww1,
    const float* __restrict__ Ww2, bf16x8* __restrict__ wsF)
{
    int c = blockIdx.x * 256 + threadIdx.x;
    if (c >= NCHUNKS) return;
    const int lane = c & 63, l16 = lane & 15, row8 = ((lane >> 4) & 3) * 8;
    bf16x8 p;
    if (c < WE2F_OFF) {                       // We1 || Wg1, pad K 136->160
        int ct = (c >> 6) & 15, kc = c >> 10;
        int col = ct * 16 + l16;
        const float* src = (col < 128) ? (We1 + col) : (Wg1 + (col - 128));
#pragma unroll
        for (int i = 0; i < 8; i++) {
            int r = kc * 32 + row8 + i;
            p[i] = (__bf16)((r < 136) ? src[(size_t)r * 128] : 0.f);
        }
    } else if (c < WN1F_OFF) {
        int cc = c - WE2F_OFF; int ct = (cc >> 6) & 3, kc = cc >> 8;
        int col = ct * 16 + l16;
#pragma unroll
        for (int i = 0; i < 8; i++)
            p[i] = (__bf16)We2[(size_t)(kc * 32 + row8 + i) * 64 + col];
    } else if (c < WN2F_OFF) {
        int cc = c - WN1F_OFF; int ct = (cc >> 6) & 7, kc = cc >> 9;
        int col = ct * 16 + l16;
#pragma unroll
        for (int i = 0; i < 8; i++)
            p[i] = (__bf16)Wn1[(size_t)(kc * 32 + row8 + i) * 128 + col];
    } else if (c < WW1F_OFF) {
        int cc = c - WN2F_OFF; int ct = (cc >> 6) & 3, kc = cc >> 8;
        int col = ct * 16 + l16;
#pragma unroll
        for (int i = 0; i < 8; i++)
            p[i] = (__bf16)Wn2[(size_t)(kc * 32 + row8 + i) * 64 + col];
    } else if (c < WW2F_OFF) {                // Ww1, pad K 67->96
        int cc = c - WW1F_OFF; int ct = (cc >> 6) & 7, kc = cc >> 9;
        int col = ct * 16 + l16;
#pragma unroll
        for (int i = 0; i < 8; i++) {
            int r = kc * 32 + row8 + i;
            p[i] = (__bf16)((r < 67) ? Ww1[(size_t)r * 128 + col] : 0.f);
        }
    } else {
        int cc = c - WW2F_OFF; int ct = (cc >> 6) & 3, kc = cc >> 8;
        int col = ct * 16 + l16;
#pragma unroll
        for (int i = 0; i < 8; i++)
            p[i] = (__bf16)Ww2[(size_t)(kc * 32 + row8 + i) * 64 + col];
    }
    wsF[c] = p;
}

// ---------------- world kernel: 512 thr, N-split, weights once/block ----------
__global__ __launch_bounds__(512, 4) void world_kernel(
    const float* __restrict__ z_h, const float* __restrict__ pos_world,
    const bf16x8* __restrict__ Ww1F, const bf16x8* __restrict__ Ww2F,
    const float* __restrict__ bw1, const float* __restrict__ bw2,
    float* __restrict__ m_agg_w)
{
    __shared__ union { bf16x8 XF[768]; bf16x8 HF[1024]; } U;   // 16 KB
    const int t = threadIdx.x;
    const int n0 = blockIdx.x * 64;
    const int lane = t & 63, w = t >> 6;
    const int quad = lane >> 4, l16 = lane & 15;

    {   // gather: 8 threads/node; q<4: z quarters; q==4: diff feats; q>=5: pad
        int nn = t >> 3, q = t & 7;
        int mt = nn >> 4, l16e = nn & 15;
        int node = n0 + nn; if (node >= NN) node = NN - 1;
        if (q < 4) {
            const float4* zr = (const float4*)(z_h + (long)node * 64) + q * 4;
            float4 a0 = zr[0], a1 = zr[1], a2 = zr[2], a3 = zr[3];
            int kcs = q >> 1, qa = (q & 1) * 2;
            U.XF[(kcs * 4 + mt) * 64 + qa * 16 + l16e]       = pack8(a0, a1);
            U.XF[(kcs * 4 + mt) * 64 + (qa + 1) * 16 + l16e] = pack8(a2, a3);
        } else if (q == 4) {
            float4 a0 = *(const float4*)(z_h + (long)node * 64);
            bf16x8 f;
#pragma unroll
            for (int i = 0; i < 8; i++) f[i] = (__bf16)0.f;
            f[0] = (__bf16)(a0.x - pos_world[0]);
            f[1] = (__bf16)(a0.y - pos_world[1]);
            f[2] = (__bf16)(a0.z - pos_world[2]);
            U.XF[(8 + mt) * 64 + l16e] = f;
        } else {
            bf16x8 z;
#pragma unroll
            for (int i = 0; i < 8; i++) z[i] = (__bf16)0.f;
            U.XF[(8 + mt) * 64 + (q - 4) * 16 + l16e] = z;
        }
    }
    __syncthreads();                         // B1: XF ready

    // GEMM1: wave owns n-tile w (16 of 128 hidden cols)
    f32x4 acc[4];
    {
        float b = bw1[w * 16 + l16];
#pragma unroll
        for (int mt = 0; mt < 4; mt++) { f32x4 v = {b, b, b, b}; acc[mt] = v; }
    }
#pragma unroll
    for (int kc = 0; kc < 3; kc++) {
        bf16x8 bfr = Ww1F[(kc * 8 + w) * 64 + lane];
#pragma unroll
        for (int mt = 0; mt < 4; mt++)
            acc[mt] = __builtin_amdgcn_mfma_f32_16x16x32_bf16(
                U.XF[(kc * 4 + mt) * 64 + lane], bfr, acc[mt], 0, 0, 0);
    }
    __syncthreads();                         // B2: XF reads done

    {   // relu + transpose -> HF
        __bf16* HFp = (__bf16*)U.HF;
        int cw = w * 16 + l16;
        int kc2 = cw >> 5, quad2 = (cw >> 3) & 3, ii = cw & 7;
#pragma unroll
        for (int mt = 0; mt < 4; mt++)
#pragma unroll
            for (int r = 0; r < 4; r++)
                HFp[(((kc2 * 4 + mt) * 64) + quad2 * 16 + quad * 4 + r) * 8 + ii] =
                    (__bf16)fmaxf(acc[mt][r], 0.f);
    }
    __syncthreads();                         // B3: HF ready

    // GEMM2 + masked column-sum: nt = w&3, m-half mh = w>>2
    {
        const int nt = w & 3, mh = w >> 2;
        f32x4 acc2[2];
        float b2 = bw2[nt * 16 + l16];
#pragma unroll
        for (int m = 0; m < 2; m++) { f32x4 v = {b2, b2, b2, b2}; acc2[m] = v; }
#pragma unroll
        for (int kc = 0; kc < 4; kc++) {
            bf16x8 b2f = Ww2F[(kc * 4 + nt) * 64 + lane];
#pragma unroll
            for (int m = 0; m < 2; m++)
                acc2[m] = __builtin_amdgcn_mfma_f32_16x16x32_bf16(
                    U.HF[(kc * 4 + mh * 2 + m) * 64 + lane], b2f, acc2[m], 0, 0, 0);
        }
        float s = 0.f;
#pragma unroll
        for (int m = 0; m < 2; m++)
#pragma unroll
            for (int r = 0; r < 4; r++) {
                int node = n0 + (mh * 2 + m) * 16 + quad * 4 + r;
                s += (node < NN) ? acc2[m][r] : 0.f;
            }
        s += __shfl_xor(s, 16, 64);
        s += __shfl_xor(s, 32, 64);
        if (quad == 0) atomicAdd(m_agg_w + nt * 16 + l16, s);
    }
}

// ---------------- edge kernel: M=128 edges/block, 8 waves, N-split ----------
union EdgeU { bf16x8 XF[2560]; bf16x8 HF[2048]; };   // 40 KB

__global__ __launch_bounds__(512, 3) void edge_kernel(
    const float* __restrict__ z_h, const int* __restrict__ ei,
    const bf16x8* __restrict__ We1F, const bf16x8* __restrict__ We2F,
    const float* __restrict__ be1, const float* __restrict__ be2,
    const float* __restrict__ bg1, const float* __restrict__ Wg2,
    const float* __restrict__ bg2,
    float* __restrict__ m_agg_h)
{
    __shared__ EdgeU U;
    __shared__ int   tgt_s[128];
    __shared__ float gred[4][128];
    __shared__ float wgt[128];

    const int t = threadIdx.x;               // 0..511
    const int e0 = blockIdx.x * 128;         // NE % 128 == 0
    const int lane = t & 63, w = t >> 6;     // w 0..7
    const int quad = lane >> 4, l16 = lane & 15;

#pragma unroll
    for (int i = 0; i < 2; i++) {            // gather: 8 threads/edge, 2 rounds
        int ee = i * 64 + (t >> 3), q = t & 7;
        int side = q >> 2, sub = q & 3;
        int mt = ee >> 4, l16e = ee & 15;
        int eg = e0 + ee;
        int row = side ? ei[NE + eg] : ei[eg];
        if (q == 4) tgt_s[ee] = row;
        const float4* zr = (const float4*)(z_h + (long)row * 64) + sub * 4;
        float4 a0 = zr[0], a1 = zr[1], a2 = zr[2], a3 = zr[3];
        int kcs = (sub >> 1) + side * 2, qa = (sub & 1) * 2;
        U.XF[(kcs * 8 + mt) * 64 + qa * 16 + l16e]       = pack8(a0, a1);
        U.XF[(kcs * 8 + mt) * 64 + (qa + 1) * 16 + l16e] = pack8(a2, a3);
        if (q == 0) {       // edge features (cols 128..135)
            const float4* zt = (const float4*)(z_h + (long)ei[NE + eg] * 64);
            float4 t0 = zt[0], t1 = zt[1];
            float dx = a0.x - t0.x, dy = a0.y - t0.y, dz = a0.z - t0.z;
            float ax = a0.w, ay = a1.x, az = a1.y;
            float bx = t0.w, by = t1.x, bz = t1.y;
            float cx = ay * bz - az * by;
            float cy = az * bx - ax * bz;
            float cz = ax * by - ay * bx;
            bf16x8 f;
            f[0] = (__bf16)dx; f[1] = (__bf16)dy; f[2] = (__bf16)dz;
            f[3] = (__bf16)(dx * dx + dy * dy + dz * dz);
            f[4] = (__bf16)cx; f[5] = (__bf16)cy; f[6] = (__bf16)cz;
            f[7] = (__bf16)sqrtf(cx * cx + cy * cy + cz * cz);
            U.XF[(32 + mt) * 64 + l16e] = f;
        } else if (q >= 5) { // zero pad (cols 136..159)
            bf16x8 z;
#pragma unroll
            for (int k = 0; k < 8; k++) z[k] = (__bf16)0.f;
            U.XF[(32 + mt) * 64 + (q - 4) * 16 + l16e] = z;
        }
    }
    __syncthreads();                         // B1: XF ready

    // ---- GEMM1: wave owns 32 cols (tiles 2w, 2w+1); M=128 (8 m-tiles) ----
    f32x4 acc[8][2];
#pragma unroll
    for (int nt = 0; nt < 2; nt++) {
        int col = (w * 2 + nt) * 16 + l16;
        float b = (col < 128) ? be1[col] : bg1[col - 128];
#pragma unroll
        for (int mt = 0; mt < 8; mt++) { f32x4 v = {b, b, b, b}; acc[mt][nt] = v; }
    }
#pragma unroll
    for (int kc = 0; kc < 5; kc++) {
        bf16x8 bfr0 = We1F[(kc * 16 + w * 2) * 64 + lane];
        bf16x8 bfr1 = We1F[(kc * 16 + w * 2 + 1) * 64 + lane];
#pragma unroll
        for (int mt = 0; mt < 8; mt++) {
            bf16x8 af = U.XF[(kc * 8 + mt) * 64 + lane];
            acc[mt][0] = __builtin_amdgcn_mfma_f32_16x16x32_bf16(af, bfr0, acc[mt][0], 0, 0, 0);
            acc[mt][1] = __builtin_amdgcn_mfma_f32_16x16x32_bf16(af, bfr1, acc[mt][1], 0, 0, 0);
        }
    }
    __syncthreads();                         // B2: XF reads done (HF may overwrite)

    if (w < 4) {
        // ---- message waves: relu + transpose into HF (GEMM2-A order) ----
        __bf16* HFp = (__bf16*)U.HF;
#pragma unroll
        for (int nt = 0; nt < 2; nt++) {
            int cw = (w * 2 + nt) * 16 + l16;
            int kc2 = cw >> 5, quad2 = (cw >> 3) & 3, ii = cw & 7;
#pragma unroll
            for (int mt = 0; mt < 8; mt++)
#pragma unroll
                for (int r = 0; r < 4; r++)
                    HFp[(((kc2 * 8 + mt) * 64) + quad2 * 16 + quad * 4 + r) * 8 + ii] =
                        (__bf16)fmaxf(acc[mt][nt][r], 0.f);
        }
    } else {
        // ---- gate waves: in-register partials over their 32 gate cols ----
        float gp[8][4];
#pragma unroll
        for (int mt = 0; mt < 8; mt++)
#pragma unroll
            for (int r = 0; r < 4; r++) gp[mt][r] = 0.f;
#pragma unroll
        for (int nt = 0; nt < 2; nt++) {
            float wg = Wg2[((w - 4) * 2 + nt) * 16 + l16];
#pragma unroll
            for (int mt = 0; mt < 8; mt++)
#pragma unroll
                for (int r = 0; r < 4; r++)
                    gp[mt][r] += fmaxf(acc[mt][nt][r], 0.f) * wg;
        }
#pragma unroll
        for (int mask = 1; mask < 16; mask <<= 1)
#pragma unroll
            for (int mt = 0; mt < 8; mt++)
#pragma unroll
                for (int r = 0; r < 4; r++)
                    gp[mt][r] += __shfl_xor(gp[mt][r], mask, 64);
        if (l16 == 0) {
#pragma unroll
            for (int mt = 0; mt < 8; mt++)
#pragma unroll
                for (int r = 0; r < 4; r++)
                    gred[w - 4][mt * 16 + quad * 4 + r] = gp[mt][r];
        }
    }
    __syncthreads();                         // B3: HF + gred ready

    if (t < 128) {                           // 128 sigmoids/block (waves 0-1)
        float g = bg2[0] + gred[0][t] + gred[1][t] + gred[2][t] + gred[3][t];
        wgt[t] = 1.f / (1.f + __expf(-g));
    }

    // ---- GEMM2 (all 8 waves): nt = w&3, m-half mh = w>>2 ----
    const int nt2 = w & 3, mh = w >> 2;
    f32x4 acc2[4];
    {
        float b2 = be2[nt2 * 16 + l16];
#pragma unroll
        for (int m = 0; m < 4; m++) { f32x4 v = {b2, b2, b2, b2}; acc2[m] = v; }
    }
#pragma unroll
    for (int kc = 0; kc < 4; kc++) {
        bf16x8 b2f = We2F[(kc * 4 + nt2) * 64 + lane];
#pragma unroll
        for (int m = 0; m < 4; m++)
            acc2[m] = __builtin_amdgcn_mfma_f32_16x16x32_bf16(
                U.HF[(kc * 8 + mh * 4 + m) * 64 + lane], b2f, acc2[m], 0, 0, 0);
    }
    __syncthreads();                         // B4: wgt ready

#pragma unroll
    for (int m = 0; m < 4; m++)
#pragma unroll
        for (int r = 0; r < 4; r++) {
            int edge = (mh * 4 + m) * 16 + quad * 4 + r;
            atomicAdd(m_agg_h + (long)tgt_s[edge] * 64 + nt2 * 16 + l16,
                      acc2[m][r] * wgt[edge]);
        }
}

// ---------------- node kernel: 512 thr, N-split, weights once/block ---------
__global__ __launch_bounds__(512, 4) void node_kernel(
    const float* __restrict__ z_h,
    const float* __restrict__ m_agg_h, const float* __restrict__ m_agg_w,
    const bf16x8* __restrict__ Wn1F, const bf16x8* __restrict__ Wn2F,
    const float* __restrict__ bn1, const float* __restrict__ bn2,
    float* __restrict__ outp)
{
    __shared__ union { bf16x8 XF[1024]; bf16x8 HF[1024]; } U;   // 16 KB
    const int t = threadIdx.x;
    const int n0 = blockIdx.x * 64;
    const int lane = t & 63, w = t >> 6;
    const int quad = lane >> 4, l16 = lane & 15;

    {   // gather: 8 threads/node; halves: z | m_agg_h + m_agg_w
        int nn = t >> 3, q = t & 7;
        int mt = nn >> 4, l16e = nn & 15;
        int node = n0 + nn; if (node >= NN) node = NN - 1;
        int half = q >> 2, sub = q & 3;
        float4 a0, a1, a2, a3;
        if (half == 0) {
            const float4* zr = (const float4*)(z_h + (long)node * 64) + sub * 4;
            a0 = zr[0]; a1 = zr[1]; a2 = zr[2]; a3 = zr[3];
        } else {
            const float4* mr = (const float4*)(m_agg_h + (long)node * 64) + sub * 4;
            const float4* mw = (const float4*)m_agg_w + sub * 4;
            a0 = add4(mr[0], mw[0]); a1 = add4(mr[1], mw[1]);
            a2 = add4(mr[2], mw[2]); a3 = add4(mr[3], mw[3]);
        }
        int kcs = (sub >> 1) + half * 2, qa = (sub & 1) * 2;
        U.XF[(kcs * 4 + mt) * 64 + qa * 16 + l16e]       = pack8(a0, a1);
        U.XF[(kcs * 4 + mt) * 64 + (qa + 1) * 16 + l16e] = pack8(a2, a3);
    }
    __syncthreads();                         // B1

    f32x4 acc[4];
    {
        float b = bn1[w * 16 + l16];
#pragma unroll
        for (int mt = 0; mt < 4; mt++) { f32x4 v = {b, b, b, b}; acc[mt] = v; }
    }
#pragma unroll
    for (int kc = 0; kc < 4; kc++) {
        bf16x8 bfr = Wn1F[(kc * 8 + w) * 64 + lane];
#pragma unroll
        for (int mt = 0; mt < 4; mt++)
            acc[mt] = __builtin_amdgcn_mfma_f32_16x16x32_bf16(
                U.XF[(kc * 4 + mt) * 64 + lane], bfr, acc[mt], 0, 0, 0);
    }
    __syncthreads();                         // B2

    {   // relu + transpose -> HF
        __bf16* HFp = (__bf16*)U.HF;
        int cw = w * 16 + l16;
        int kc2 = cw >> 5, quad2 = (cw >> 3) & 3, ii = cw & 7;
#pragma unroll
        for (int mt = 0; mt < 4; mt++)
#pragma unroll
            for (int r = 0; r < 4; r++)
                HFp[(((kc2 * 4 + mt) * 64) + quad2 * 16 + quad * 4 + r) * 8 + ii] =
                    (__bf16)fmaxf(acc[mt][r], 0.f);
    }
    __syncthreads();                         // B3

    {   // GEMM2 + store: nt = w&3, m-half mh = w>>2
        const int nt = w & 3, mh = w >> 2;
        f32x4 acc2[2];
        float b2 = bn2[nt * 16 + l16];
#pragma unroll
        for (int m = 0; m < 2; m++) { f32x4 v = {b2, b2, b2, b2}; acc2[m] = v; }
#pragma unroll
        for (int kc = 0; kc < 4; kc++) {
            bf16x8 b2f = Wn2F[(kc * 4 + nt) * 64 + lane];
#pragma unroll
            for (int m = 0; m < 2; m++)
                acc2[m] = __builtin_amdgcn_mfma_f32_16x16x32_bf16(
                    U.HF[(kc * 4 + mh * 2 + m) * 64 + lane], b2f, acc2[m], 0, 0, 0);
        }
#pragma unroll
        for (int m = 0; m < 2; m++)
#pragma unroll
            for (int r = 0; r < 4; r++) {
                int node = n0 + (mh * 2 + m) * 16 + quad * 4 + r;
                if (node < NN)
                    outp[(long)node * 64 + nt * 16 + l16] = acc2[m][r];
            }
    }
}

extern "C" void kernel_launch(void* const* d_in, const int* in_sizes, int n_in,
                              void* d_out, int out_size, void* d_ws, size_t ws_size,
                              hipStream_t stream)
{
    const float* z_h       = (const float*)d_in[0];
    const float* pos_world = (const float*)d_in[1];
    const int*   ei        = (const int*)d_in[2];
    const float* We1 = (const float*)d_in[3];  const float* be1 = (const float*)d_in[4];
    const float* We2 = (const float*)d_in[5];  const float* be2 = (const float*)d_in[6];
    const float* Wg1 = (const float*)d_in[7];  const float* bg1 = (const float*)d_in[8];
    const float* Wg2 = (const float*)d_in[9];  const float* bg2 = (const float*)d_in[10];
    const float* Wn1 = (const float*)d_in[11]; const float* bn1 = (const float*)d_in[12];
    const float* Wn2 = (const float*)d_in[13]; const float* bn2 = (const float*)d_in[14];
    const float* Ww1 = (const float*)d_in[15]; const float* bw1 = (const float*)d_in[16];
    const float* Ww2 = (const float*)d_in[17]; const float* bw2 = (const float*)d_in[18];

    float*  outp    = (float*)d_out;
    float*  m_agg_h = outp;                 // d_out doubles as scatter accumulator
    float*  m_agg_w = (float*)d_ws;         // 64 floats
    bf16x8* wsF     = (bf16x8*)((char*)d_ws + 256);

    hipMemsetAsync(d_out, 0, (size_t)NN * 64 * sizeof(float), stream);
    hipMemsetAsync(d_ws, 0, 256, stream);

    pack_weights<<<(NCHUNKS + 255) / 256, 256, 0, stream>>>(
        We1, Wg1, We2, Wn1, Wn2, Ww1, Ww2, wsF);
    world_kernel<<<(NN + 63) / 64, 512, 0, stream>>>(
        z_h, pos_world, wsF + WW1F_OFF, wsF + WW2F_OFF, bw1, bw2, m_agg_w);
    edge_kernel<<<NE / 128, 512, 0, stream>>>(
        z_h, ei, wsF + WE1F_OFF, wsF + WE2F_OFF,
        be1, be2, bg1, Wg2, bg2, m_agg_h);
    node_kernel<<<(NN + 63) / 64, 512, 0, stream>>>(
        z_h, m_agg_h, m_agg_w, wsF + WN1F_OFF, wsF + WN2F_OFF, bn1, bn2, outp);
}

// Round 8
// 346.681 us; speedup vs baseline: 1.1437x; 1.1437x over previous
//
#include <hip/hip_runtime.h>
#include <math.h>

#define NN 50000
#define NE 800000
#define EBLOCKS (NE / 64)          // 12500 edge blocks
#define WBLOCKS ((NN + 63) / 64)   // 782 world blocks

typedef float  f32x4  __attribute__((ext_vector_type(4)));
typedef __bf16 bf16x8 __attribute__((ext_vector_type(8)));

// ws layout: [0,256) m_agg_w (64 f32). [256,...) bf16 weight fragments,
// 16B chunks, fragment-linear (chunk = tile*64 + lane):
#define WE1F_OFF 0        // 5120: We1||Wg1  (kc<5, ct<16)  K 136->160
#define WE2F_OFF 5120     // 1024: We2       (kc<4, ct<4)
#define WN1F_OFF 6144     // 2048: Wn1       (kc<4, ct<8)
#define WN2F_OFF 8192     // 1024: Wn2       (kc<4, ct<4)
#define WW1F_OFF 9216     // 1536: Ww1       (kc<3, ct<8)   K 67->96
#define WW2F_OFF 10752    // 1024: Ww2       (kc<4, ct<4)
#define NCHUNKS  11776

__device__ inline bf16x8 pack8(float4 a, float4 b) {
    bf16x8 r;
    r[0] = (__bf16)a.x; r[1] = (__bf16)a.y; r[2] = (__bf16)a.z; r[3] = (__bf16)a.w;
    r[4] = (__bf16)b.x; r[5] = (__bf16)b.y; r[6] = (__bf16)b.z; r[7] = (__bf16)b.w;
    return r;
}

__device__ inline float4 add4(float4 a, float4 b) {
    a.x += b.x; a.y += b.y; a.z += b.z; a.w += b.w; return a;
}

// ---------------- weight fragment pre-pack ----------------
__global__ __launch_bounds__(256) void pack_weights(
    const float* __restrict__ We1, const float* __restrict__ Wg1,
    const float* __restrict__ We2, const float* __restrict__ Wn1,
    const float* __restrict__ Wn2, const float* __restrict__ Ww1,
    const float* __restrict__ Ww2, bf16x8* __restrict__ wsF)
{
    int c = blockIdx.x * 256 + threadIdx.x;
    if (c >= NCHUNKS) return;
    const int lane = c & 63, l16 = lane & 15, row8 = ((lane >> 4) & 3) * 8;
    bf16x8 p;
    if (c < WE2F_OFF) {                       // We1 || Wg1, pad K 136->160
        int ct = (c >> 6) & 15, kc = c >> 10;
        int col = ct * 16 + l16;
        const float* src = (col < 128) ? (We1 + col) : (Wg1 + (col - 128));
#pragma unroll
        for (int i = 0; i < 8; i++) {
            int r = kc * 32 + row8 + i;
            p[i] = (__bf16)((r < 136) ? src[(size_t)r * 128] : 0.f);
        }
    } else if (c < WN1F_OFF) {
        int cc = c - WE2F_OFF; int ct = (cc >> 6) & 3, kc = cc >> 8;
        int col = ct * 16 + l16;
#pragma unroll
        for (int i = 0; i < 8; i++)
            p[i] = (__bf16)We2[(size_t)(kc * 32 + row8 + i) * 64 + col];
    } else if (c < WN2F_OFF) {
        int cc = c - WN1F_OFF; int ct = (cc >> 6) & 7, kc = cc >> 9;
        int col = ct * 16 + l16;
#pragma unroll
        for (int i = 0; i < 8; i++)
            p[i] = (__bf16)Wn1[(size_t)(kc * 32 + row8 + i) * 128 + col];
    } else if (c < WW1F_OFF) {
        int cc = c - WN2F_OFF; int ct = (cc >> 6) & 3, kc = cc >> 8;
        int col = ct * 16 + l16;
#pragma unroll
        for (int i = 0; i < 8; i++)
            p[i] = (__bf16)Wn2[(size_t)(kc * 32 + row8 + i) * 64 + col];
    } else if (c < WW2F_OFF) {                // Ww1, pad K 67->96
        int cc = c - WW1F_OFF; int ct = (cc >> 6) & 7, kc = cc >> 9;
        int col = ct * 16 + l16;
#pragma unroll
        for (int i = 0; i < 8; i++) {
            int r = kc * 32 + row8 + i;
            p[i] = (__bf16)((r < 67) ? Ww1[(size_t)r * 128 + col] : 0.f);
        }
    } else {
        int cc = c - WW2F_OFF; int ct = (cc >> 6) & 3, kc = cc >> 8;
        int col = ct * 16 + l16;
#pragma unroll
        for (int i = 0; i < 8; i++)
            p[i] = (__bf16)Ww2[(size_t)(kc * 32 + row8 + i) * 64 + col];
    }
    wsF[c] = p;
}

// --------- fused edge + world kernel: blocks [0,EBLOCKS) = edges, rest = world
// Edge path: R6 structure — 64 edges/block, 8 waves, wave owns 2 GEMM1
// col-tiles (waves 0-3 message, 4-7 gate), weights read once/block with
// register double-buffer prefetch. World path: R7 structure.
union FusedLds {
    bf16x8 XF[1280];     // edge XF 20 KB (world uses first 768)
    bf16x8 HF[1024];     // HF 16 KB (both paths)
};

__global__ __launch_bounds__(512, 6) void fused_kernel(
    const float* __restrict__ z_h, const int* __restrict__ ei,
    const bf16x8* __restrict__ We1F, const bf16x8* __restrict__ We2F,
    const float* __restrict__ be1, const float* __restrict__ be2,
    const float* __restrict__ bg1, const float* __restrict__ Wg2,
    const float* __restrict__ bg2,
    const float* __restrict__ pos_world,
    const bf16x8* __restrict__ Ww1F, const bf16x8* __restrict__ Ww2F,
    const float* __restrict__ bw1, const float* __restrict__ bw2,
    float* __restrict__ m_agg_h, float* __restrict__ m_agg_w)
{
    __shared__ FusedLds U;
    __shared__ int   tgt_s[64];
    __shared__ float gred[4][64];
    __shared__ float wgt[64];

    const int t = threadIdx.x;               // 0..511
    const int lane = t & 63, w = t >> 6;     // w 0..7
    const int quad = lane >> 4, l16 = lane & 15;

    if (blockIdx.x >= EBLOCKS) {
        // ================= world path (R7) =================
        const int n0 = (blockIdx.x - EBLOCKS) * 64;
        {   // gather
            int nn = t >> 3, q = t & 7;
            int mt = nn >> 4, l16e = nn & 15;
            int node = n0 + nn; if (node >= NN) node = NN - 1;
            if (q < 4) {
                const float4* zr = (const float4*)(z_h + (long)node * 64) + q * 4;
                float4 a0 = zr[0], a1 = zr[1], a2 = zr[2], a3 = zr[3];
                int kcs = q >> 1, qa = (q & 1) * 2;
                U.XF[(kcs * 4 + mt) * 64 + qa * 16 + l16e]       = pack8(a0, a1);
                U.XF[(kcs * 4 + mt) * 64 + (qa + 1) * 16 + l16e] = pack8(a2, a3);
            } else if (q == 4) {
                float4 a0 = *(const float4*)(z_h + (long)node * 64);
                bf16x8 f;
#pragma unroll
                for (int i = 0; i < 8; i++) f[i] = (__bf16)0.f;
                f[0] = (__bf16)(a0.x - pos_world[0]);
                f[1] = (__bf16)(a0.y - pos_world[1]);
                f[2] = (__bf16)(a0.z - pos_world[2]);
                U.XF[(8 + mt) * 64 + l16e] = f;
            } else {
                bf16x8 z;
#pragma unroll
                for (int i = 0; i < 8; i++) z[i] = (__bf16)0.f;
                U.XF[(8 + mt) * 64 + (q - 4) * 16 + l16e] = z;
            }
        }
        __syncthreads();

        f32x4 acc[4];
        {
            float b = bw1[w * 16 + l16];
#pragma unroll
            for (int mt = 0; mt < 4; mt++) { f32x4 v = {b, b, b, b}; acc[mt] = v; }
        }
#pragma unroll
        for (int kc = 0; kc < 3; kc++) {
            bf16x8 bfr = Ww1F[(kc * 8 + w) * 64 + lane];
#pragma unroll
            for (int mt = 0; mt < 4; mt++)
                acc[mt] = __builtin_amdgcn_mfma_f32_16x16x32_bf16(
                    U.XF[(kc * 4 + mt) * 64 + lane], bfr, acc[mt], 0, 0, 0);
        }
        __syncthreads();

        {   // relu + transpose -> HF
            __bf16* HFp = (__bf16*)U.HF;
            int cw = w * 16 + l16;
            int kc2 = cw >> 5, quad2 = (cw >> 3) & 3, ii = cw & 7;
#pragma unroll
            for (int mt = 0; mt < 4; mt++)
#pragma unroll
                for (int r = 0; r < 4; r++)
                    HFp[(((kc2 * 4 + mt) * 64) + quad2 * 16 + quad * 4 + r) * 8 + ii] =
                        (__bf16)fmaxf(acc[mt][r], 0.f);
        }
        __syncthreads();

        {   // GEMM2 + masked column-sum
            const int nt = w & 3, mh = w >> 2;
            f32x4 acc2[2];
            float b2 = bw2[nt * 16 + l16];
#pragma unroll
            for (int m = 0; m < 2; m++) { f32x4 v = {b2, b2, b2, b2}; acc2[m] = v; }
#pragma unroll
            for (int kc = 0; kc < 4; kc++) {
                bf16x8 b2f = Ww2F[(kc * 4 + nt) * 64 + lane];
#pragma unroll
                for (int m = 0; m < 2; m++)
                    acc2[m] = __builtin_amdgcn_mfma_f32_16x16x32_bf16(
                        U.HF[(kc * 4 + mh * 2 + m) * 64 + lane], b2f, acc2[m], 0, 0, 0);
            }
            float s = 0.f;
#pragma unroll
            for (int m = 0; m < 2; m++)
#pragma unroll
                for (int r = 0; r < 4; r++) {
                    int node = n0 + (mh * 2 + m) * 16 + quad * 4 + r;
                    s += (node < NN) ? acc2[m][r] : 0.f;
                }
            s += __shfl_xor(s, 16, 64);
            s += __shfl_xor(s, 32, 64);
            if (quad == 0) atomicAdd(m_agg_w + nt * 16 + l16, s);
        }
        return;
    }

    // ================= edge path (R6 + B-frag register dbuf) =================
    const int e0 = blockIdx.x * 64;          // NE % 64 == 0

    {   // ---- gather: 8 threads/edge (side 0 = src, side 1 = tgt) ----
        const int ee = t >> 3, q = t & 7;
        const int side = q >> 2, sub = q & 3;
        const int mt = ee >> 4, l16e = ee & 15;
        const int eg = e0 + ee;
        const int row = side ? ei[NE + eg] : ei[eg];
        if (q == 4) tgt_s[ee] = row;
        const float4* zr = (const float4*)(z_h + (long)row * 64) + sub * 4;
        float4 a0 = zr[0], a1 = zr[1], a2 = zr[2], a3 = zr[3];
        const int kcs = (sub >> 1) + side * 2, qa = (sub & 1) * 2;
        U.XF[(kcs * 4 + mt) * 64 + qa * 16 + l16e]       = pack8(a0, a1);
        U.XF[(kcs * 4 + mt) * 64 + (qa + 1) * 16 + l16e] = pack8(a2, a3);
        if (q == 0) {       // edge features (cols 128..135)
            const float4* zt = (const float4*)(z_h + (long)ei[NE + eg] * 64);
            float4 t0 = zt[0], t1 = zt[1];
            float dx = a0.x - t0.x, dy = a0.y - t0.y, dz = a0.z - t0.z;
            float ax = a0.w, ay = a1.x, az = a1.y;
            float bx = t0.w, by = t1.x, bz = t1.y;
            float cx = ay * bz - az * by;
            float cy = az * bx - ax * bz;
            float cz = ax * by - ay * bx;
            bf16x8 f;
            f[0] = (__bf16)dx; f[1] = (__bf16)dy; f[2] = (__bf16)dz;
            f[3] = (__bf16)(dx * dx + dy * dy + dz * dz);
            f[4] = (__bf16)cx; f[5] = (__bf16)cy; f[6] = (__bf16)cz;
            f[7] = (__bf16)sqrtf(cx * cx + cy * cy + cz * cz);
            U.XF[(16 + mt) * 64 + l16e] = f;
        } else if (q >= 5) { // zero pad (cols 136..159)
            bf16x8 z;
#pragma unroll
            for (int i = 0; i < 8; i++) z[i] = (__bf16)0.f;
            U.XF[(16 + mt) * 64 + (q - 4) * 16 + l16e] = z;
        }
    }
    __syncthreads();                         // B1: XF ready

    // ---- GEMM1: wave owns 32 cols (tiles 2w, 2w+1), 1-ahead B prefetch ----
    f32x4 acc[4][2];
#pragma unroll
    for (int nt = 0; nt < 2; nt++) {
        int col = (w * 2 + nt) * 16 + l16;
        float b = (col < 128) ? be1[col] : bg1[col - 128];
#pragma unroll
        for (int mt = 0; mt < 4; mt++) { f32x4 v = {b, b, b, b}; acc[mt][nt] = v; }
    }
    bf16x8 bcur0 = We1F[(w * 2) * 64 + lane];
    bf16x8 bcur1 = We1F[(w * 2 + 1) * 64 + lane];
#pragma unroll
    for (int kc = 0; kc < 5; kc++) {
        bf16x8 bnx0, bnx1;
        if (kc < 4) {
            bnx0 = We1F[((kc + 1) * 16 + w * 2) * 64 + lane];
            bnx1 = We1F[((kc + 1) * 16 + w * 2 + 1) * 64 + lane];
        }
#pragma unroll
        for (int mt = 0; mt < 4; mt++) {
            bf16x8 af = U.XF[(kc * 4 + mt) * 64 + lane];
            acc[mt][0] = __builtin_amdgcn_mfma_f32_16x16x32_bf16(af, bcur0, acc[mt][0], 0, 0, 0);
            acc[mt][1] = __builtin_amdgcn_mfma_f32_16x16x32_bf16(af, bcur1, acc[mt][1], 0, 0, 0);
        }
        bcur0 = bnx0; bcur1 = bnx1;
    }
    __syncthreads();                         // B2: XF reads done (HF may overwrite)

    if (w < 4) {
        // ---- message waves: relu + transpose into HF (GEMM2-A order) ----
        __bf16* HFp = (__bf16*)U.HF;
#pragma unroll
        for (int nt = 0; nt < 2; nt++) {
            int cw = (w * 2 + nt) * 16 + l16;
            int kc2 = cw >> 5, quad2 = (cw >> 3) & 3, ii = cw & 7;
#pragma unroll
            for (int mt = 0; mt < 4; mt++)
#pragma unroll
                for (int r = 0; r < 4; r++)
                    HFp[(((kc2 * 4 + mt) * 64) + quad2 * 16 + quad * 4 + r) * 8 + ii] =
                        (__bf16)fmaxf(acc[mt][nt][r], 0.f);
        }
    } else {
        // ---- gate waves: in-register partials over their 32 gate cols ----
        float gp[4][4];
#pragma unroll
        for (int mt = 0; mt < 4; mt++)
#pragma unroll
            for (int r = 0; r < 4; r++) gp[mt][r] = 0.f;
#pragma unroll
        for (int nt = 0; nt < 2; nt++) {
            float wg = Wg2[((w - 4) * 2 + nt) * 16 + l16];
#pragma unroll
            for (int mt = 0; mt < 4; mt++)
#pragma unroll
                for (int r = 0; r < 4; r++)
                    gp[mt][r] += fmaxf(acc[mt][nt][r], 0.f) * wg;
        }
#pragma unroll
        for (int mask = 1; mask < 16; mask <<= 1)
#pragma unroll
            for (int mt = 0; mt < 4; mt++)
#pragma unroll
                for (int r = 0; r < 4; r++)
                    gp[mt][r] += __shfl_xor(gp[mt][r], mask, 64);
        if (l16 == 0) {
#pragma unroll
            for (int mt = 0; mt < 4; mt++)
#pragma unroll
                for (int r = 0; r < 4; r++)
                    gred[(w - 4) & 3][mt * 16 + quad * 4 + r] = gp[mt][r];
        }
    }
    __syncthreads();                         // B3: HF + gred ready

    if (t < 64) {                            // 64 sigmoids per block
        float g = bg2[0] + gred[0][t] + gred[1][t] + gred[2][t] + gred[3][t];
        wgt[t] = 1.f / (1.f + __expf(-g));
    }

    // ---- GEMM2 (waves 0-3): message = H @ We2 + be2, 1-ahead B prefetch ----
    f32x4 acc2[4];
    if (w < 4) {
        float b2 = be2[w * 16 + l16];
#pragma unroll
        for (int mt = 0; mt < 4; mt++) { f32x4 v = {b2, b2, b2, b2}; acc2[mt] = v; }
        bf16x8 c2 = We2F[w * 64 + lane];
#pragma unroll
        for (int kc = 0; kc < 4; kc++) {
            bf16x8 n2;
            if (kc < 3) n2 = We2F[((kc + 1) * 4 + w) * 64 + lane];
#pragma unroll
            for (int mt = 0; mt < 4; mt++)
                acc2[mt] = __builtin_amdgcn_mfma_f32_16x16x32_bf16(
                    U.HF[(kc * 4 + mt) * 64 + lane], c2, acc2[mt], 0, 0, 0);
            c2 = n2;
        }
    }
    __syncthreads();                         // B4: wgt ready

    if (w < 4) {
        // ---- scatter: w * m -> target rows ----
#pragma unroll
        for (int mt = 0; mt < 4; mt++)
#pragma unroll
            for (int r = 0; r < 4; r++) {
                int edge = mt * 16 + quad * 4 + r;
                atomicAdd(m_agg_h + (long)tgt_s[edge] * 64 + w * 16 + l16,
                          acc2[mt][r] * wgt[edge]);
            }
    }
}

// ---------------- node kernel: 512 thr, N-split, weights once/block ---------
__global__ __launch_bounds__(512, 4) void node_kernel(
    const float* __restrict__ z_h,
    const float* __restrict__ m_agg_h, const float* __restrict__ m_agg_w,
    const bf16x8* __restrict__ Wn1F, const bf16x8* __restrict__ Wn2F,
    const float* __restrict__ bn1, const float* __restrict__ bn2,
    float* __restrict__ outp)
{
    __shared__ union { bf16x8 XF[1024]; bf16x8 HF[1024]; } U;   // 16 KB
    const int t = threadIdx.x;
    const int n0 = blockIdx.x * 64;
    const int lane = t & 63, w = t >> 6;
    const int quad = lane >> 4, l16 = lane & 15;

    {   // gather: 8 threads/node; halves: z | m_agg_h + m_agg_w
        int nn = t >> 3, q = t & 7;
        int mt = nn >> 4, l16e = nn & 15;
        int node = n0 + nn; if (node >= NN) node = NN - 1;
        int half = q >> 2, sub = q & 3;
        float4 a0, a1, a2, a3;
        if (half == 0) {
            const float4* zr = (const float4*)(z_h + (long)node * 64) + sub * 4;
            a0 = zr[0]; a1 = zr[1]; a2 = zr[2]; a3 = zr[3];
        } else {
            const float4* mr = (const float4*)(m_agg_h + (long)node * 64) + sub * 4;
            const float4* mw = (const float4*)m_agg_w + sub * 4;
            a0 = add4(mr[0], mw[0]); a1 = add4(mr[1], mw[1]);
            a2 = add4(mr[2], mw[2]); a3 = add4(mr[3], mw[3]);
        }
        int kcs = (sub >> 1) + half * 2, qa = (sub & 1) * 2;
        U.XF[(kcs * 4 + mt) * 64 + qa * 16 + l16e]       = pack8(a0, a1);
        U.XF[(kcs * 4 + mt) * 64 + (qa + 1) * 16 + l16e] = pack8(a2, a3);
    }
    __syncthreads();                         // B1

    f32x4 acc[4];
    {
        float b = bn1[w * 16 + l16];
#pragma unroll
        for (int mt = 0; mt < 4; mt++) { f32x4 v = {b, b, b, b}; acc[mt] = v; }
    }
#pragma unroll
    for (int kc = 0; kc < 4; kc++) {
        bf16x8 bfr = Wn1F[(kc * 8 + w) * 64 + lane];
#pragma unroll
        for (int mt = 0; mt < 4; mt++)
            acc[mt] = __builtin_amdgcn_mfma_f32_16x16x32_bf16(
                U.XF[(kc * 4 + mt) * 64 + lane], bfr, acc[mt], 0, 0, 0);
    }
    __syncthreads();                         // B2

    {   // relu + transpose -> HF
        __bf16* HFp = (__bf16*)U.HF;
        int cw = w * 16 + l16;
        int kc2 = cw >> 5, quad2 = (cw >> 3) & 3, ii = cw & 7;
#pragma unroll
        for (int mt = 0; mt < 4; mt++)
#pragma unroll
            for (int r = 0; r < 4; r++)
                HFp[(((kc2 * 4 + mt) * 64) + quad2 * 16 + quad * 4 + r) * 8 + ii] =
                    (__bf16)fmaxf(acc[mt][r], 0.f);
    }
    __syncthreads();                         // B3

    {   // GEMM2 + store: nt = w&3, m-half mh = w>>2
        const int nt = w & 3, mh = w >> 2;
        f32x4 acc2[2];
        float b2 = bn2[nt * 16 + l16];
#pragma unroll
        for (int m = 0; m < 2; m++) { f32x4 v = {b2, b2, b2, b2}; acc2[m] = v; }
#pragma unroll
        for (int kc = 0; kc < 4; kc++) {
            bf16x8 b2f = Wn2F[(kc * 4 + nt) * 64 + lane];
#pragma unroll
            for (int m = 0; m < 2; m++)
                acc2[m] = __builtin_amdgcn_mfma_f32_16x16x32_bf16(
                    U.HF[(kc * 4 + mh * 2 + m) * 64 + lane], b2f, acc2[m], 0, 0, 0);
        }
#pragma unroll
        for (int m = 0; m < 2; m++)
#pragma unroll
            for (int r = 0; r < 4; r++) {
                int node = n0 + (mh * 2 + m) * 16 + quad * 4 + r;
                if (node < NN)
                    outp[(long)node * 64 + nt * 16 + l16] = acc2[m][r];
            }
    }
}

extern "C" void kernel_launch(void* const* d_in, const int* in_sizes, int n_in,
                              void* d_out, int out_size, void* d_ws, size_t ws_size,
                              hipStream_t stream)
{
    const float* z_h       = (const float*)d_in[0];
    const float* pos_world = (const float*)d_in[1];
    const int*   ei        = (const int*)d_in[2];
    const float* We1 = (const float*)d_in[3];  const float* be1 = (const float*)d_in[4];
    const float* We2 = (const float*)d_in[5];  const float* be2 = (const float*)d_in[6];
    const float* Wg1 = (const float*)d_in[7];  const float* bg1 = (const float*)d_in[8];
    const float* Wg2 = (const float*)d_in[9];  const float* bg2 = (const float*)d_in[10];
    const float* Wn1 = (const float*)d_in[11]; const float* bn1 = (const float*)d_in[12];
    const float* Wn2 = (const float*)d_in[13]; const float* bn2 = (const float*)d_in[14];
    const float* Ww1 = (const float*)d_in[15]; const float* bw1 = (const float*)d_in[16];
    const float* Ww2 = (const float*)d_in[17]; const float* bw2 = (const float*)d_in[18];

    float*  outp    = (float*)d_out;
    float*  m_agg_h = outp;                 // d_out doubles as scatter accumulator
    float*  m_agg_w = (float*)d_ws;         // 64 floats
    bf16x8* wsF     = (bf16x8*)((char*)d_ws + 256);

    hipMemsetAsync(d_out, 0, (size_t)NN * 64 * sizeof(float), stream);
    hipMemsetAsync(d_ws, 0, 256, stream);

    pack_weights<<<(NCHUNKS + 255) / 256, 256, 0, stream>>>(
        We1, Wg1, We2, Wn1, Wn2, Ww1, Ww2, wsF);
    fused_kernel<<<EBLOCKS + WBLOCKS, 512, 0, stream>>>(
        z_h, ei, wsF + WE1F_OFF, wsF + WE2F_OFF,
        be1, be2, bg1, Wg2, bg2,
        pos_world, wsF + WW1F_OFF, wsF + WW2F_OFF, bw1, bw2,
        m_agg_h, m_agg_w);
    node_kernel<<<(NN + 63) / 64, 512, 0, stream>>>(
        z_h, m_agg_h, m_agg_w, wsF + WN1F_OFF, wsF + WN2F_OFF, bn1, bn2, outp);
}